// Round 14
// baseline (2138.576 us; speedup 1.0000x reference)
//
#include <hip/hip_runtime.h>

#define BB 8
#define TT 4096
#define DD 768
#define MM (BB*TT)   // 32768

typedef _Float16 f16;
typedef _Float16 f16x8 __attribute__((ext_vector_type(8)));
typedef float f32x4 __attribute__((ext_vector_type(4)));

typedef __attribute__((address_space(1))) void void_g;
typedef __attribute__((address_space(3))) void void_l;

// async global->LDS, 16B per lane. LDS dest = wave-uniform base + lane*16 (linear).
__device__ __forceinline__ void gload16(const void* g, void* l) {
  __builtin_amdgcn_global_load_lds((void_g*)g, (void_l*)l, 16, 0, 0);
}

// ---------------- f32 -> f16 convert (for weight matrices) ----------------
__global__ void cvt_f32_f16(const float* __restrict__ in, f16* __restrict__ out, int n) {
  int i0 = (blockIdx.x * blockDim.x + threadIdx.x) * 8;
  int stride = gridDim.x * blockDim.x * 8;
  for (int i = i0; i < n; i += stride) {
    float4 a = *(const float4*)(in + i);
    float4 b = *(const float4*)(in + i + 4);
    f16x8 o;
    o[0] = (f16)a.x; o[1] = (f16)a.y; o[2] = (f16)a.z; o[3] = (f16)a.w;
    o[4] = (f16)b.x; o[5] = (f16)b.y; o[6] = (f16)b.z; o[7] = (f16)b.w;
    *(f16x8*)(out + i) = o;
  }
}

// ---------------- projection GEMM: C = A*W^T + bias -----------------------
// A: MMxDD f32 (reg-cvt staged); W: DDxDD f16 (gload16 staged, pre-swizzled
// source). frag==0: C row-major (K). frag==1: C in dc-major fragment layout:
// idx = (((row>>6)*24 + (col>>5))*4 + ((row>>4)&3))*512
//       + ((row&15) + ((col>>3)&3)*16)*8 + (col&7)
// -> wave's 4 A-fragments per dc are one contiguous 2KB run.
__global__ __launch_bounds__(256)
void proj_gemm(const float* __restrict__ Af, const f16* __restrict__ Wh,
               const float* __restrict__ bias, f16* __restrict__ C, int frag) {
  __shared__ f16 As[128 * 32];
  __shared__ f16 Ws[128 * 32];
  const int m0 = blockIdx.x * 128;
  const int n0 = blockIdx.y * 128;
  const int t = threadIdx.x;
  const int lane = t & 63;
  const int w = t >> 6;
  const int wm = (w >> 1) * 64;
  const int wn = (w & 1) * 64;
  const int fr = lane & 15, fq = lane >> 4;
  const int xst = ((t >> 3) & 3) << 3;   // A store-side swizzle (row = t>>2)
  const int xrd = ((fr >> 1) & 3) << 3;  // read-side swizzle (row = ..+fr)

  f32x4 acc[4][4] = {};

  const int e0 = t * 8;
  const int r0 = t >> 2, cA = (t & 3) * 8;
  const int e1 = 2048 + t * 8;

  // W gload16 source: linear LDS dest slot t / t+256, source col pre-swizzled
  const int c8 = ((t & 3) ^ ((t >> 3) & 3)) * 8;
  const f16* wlo = Wh + (size_t)(n0 + r0) * DD + c8;
  const f16* whi = wlo + (size_t)64 * DD;

  for (int ks = 0; ks < 24; ++ks) {
    const int k0 = ks * 32;
    // stage W (f16, async direct to LDS)
    gload16(wlo + k0, &Ws[w * 512]);
    gload16(whi + k0, &Ws[2048 + w * 512]);
    // reg-stage A with f32->f16 conversion (swizzled store)
    {
      const float* g0 = Af + (size_t)(m0 + r0) * DD + k0 + cA;
      const float* g1 = Af + (size_t)(m0 + 64 + r0) * DD + k0 + cA;
      float4 x0 = *(const float4*)g0, x1 = *(const float4*)(g0 + 4);
      float4 y0 = *(const float4*)g1, y1 = *(const float4*)(g1 + 4);
      f16x8 va, vb;
      va[0] = (f16)x0.x; va[1] = (f16)x0.y; va[2] = (f16)x0.z; va[3] = (f16)x0.w;
      va[4] = (f16)x1.x; va[5] = (f16)x1.y; va[6] = (f16)x1.z; va[7] = (f16)x1.w;
      vb[0] = (f16)y0.x; vb[1] = (f16)y0.y; vb[2] = (f16)y0.z; vb[3] = (f16)y0.w;
      vb[4] = (f16)y1.x; vb[5] = (f16)y1.y; vb[6] = (f16)y1.z; vb[7] = (f16)y1.w;
      *(f16x8*)&As[e0 ^ xst] = va;
      *(f16x8*)&As[e1 ^ xst] = vb;
    }
    __syncthreads();

    f16x8 a[4], b[4];
#pragma unroll
    for (int i = 0; i < 4; ++i)
      a[i] = *(const f16x8*)&As[(((wm + i * 16 + fr) * 32) + fq * 8) ^ xrd];
#pragma unroll
    for (int j = 0; j < 4; ++j)
      b[j] = *(const f16x8*)&Ws[(((wn + j * 16 + fr) * 32) + fq * 8) ^ xrd];
#pragma unroll
    for (int i = 0; i < 4; ++i)
#pragma unroll
      for (int j = 0; j < 4; ++j)
        acc[i][j] = __builtin_amdgcn_mfma_f32_16x16x32_f16(a[i], b[j], acc[i][j], 0, 0, 0);
    __syncthreads();
  }

#pragma unroll
  for (int j = 0; j < 4; ++j) {
    const int col = n0 + wn + j * 16 + fr;
    const float bv = bias[col];
#pragma unroll
    for (int i = 0; i < 4; ++i) {
#pragma unroll
      for (int r = 0; r < 4; ++r) {
        const int row = m0 + wm + i * 16 + fq * 4 + r;
        const f16 v = (f16)(acc[i][j][r] + bv);
        if (frag) {
          const size_t idx = (((size_t)(row >> 6) * 24 + (col >> 5)) * 4 +
                              ((row >> 4) & 3)) * 512 +
                             ((row & 15) + (((col >> 3) & 3) << 4)) * 8 + (col & 7);
          C[idx] = v;
        } else {
          C[(size_t)row * DD + col] = v;
        }
      }
    }
  }
}

// ---------------- attn12: attn11 at 6 blocks/CU (kh sixths) ---------------
// Identical structure to attn11 (dc-32 phases, one-phase-ahead Q prefetch,
// unroll-2 named ping-pong, K dbuf 16KB LDS). Single change: kh split 3->6,
// grid 1536 = 6 blocks/CU, 24 waves/CU (VGPR 76 <= 85 cap at (256,6)).
// kt counts {6,6,5,5,5,5}; H = cnt*24 (144/120, even). Partial-Z slots 12.
__global__ __launch_bounds__(256, 6)
void attn12(const f16* __restrict__ Qf, const f16* __restrict__ K,
            const int* __restrict__ mask, float* __restrict__ pzv,
            float* __restrict__ sdg) {
  __shared__ f16 Ks[2][128 * 32];

  const int bid = blockIdx.x;
  const int qs = bid / 48;
  const int kh = (bid % 48) >> 3;
  const int bb = bid & 7;
  const int t = threadIdx.x, l = t & 63, w = t >> 6;
  const int wq = w >> 1, wk = w & 1;
  const int fr = l & 15, fq = l >> 4;
  const int q0 = qs * 128;
  const float scale = 0.036084391824351613f;  // 1/sqrt(768)
  const int lo = (kh < 2) ? kh * 6 : 12 + (kh - 2) * 5;
  const int cnt = (kh < 2) ? 6 : 5;
  const int H = cnt * 24;

  const f16* Kg = K + (size_t)bb * TT * DD;

  // Qf base: 64-row group grp = bb*64 + qs*2 + wq; lane offset l*8.
  const int grp = bb * 64 + qs * 2 + wq;
  const f16* qf = Qf + (size_t)grp * 24 * 4 * 512 + (size_t)l * 8;

  // K staging: linear 16B slots t / t+256; source col-slot pre-swizzled.
  const int c8 = ((t & 3) ^ ((t >> 3) & 3)) * 8;
  const f16* klo = Kg + (size_t)(t >> 2) * DD + c8;
  const f16* khi = klo + (size_t)64 * DD;

  // K fragment read: row*32 + (fq ^ ((fr>>1)&3))*8  (conflict-free, measured)
  const int sx = (fq ^ ((fr >> 1) & 3)) * 8;
  const int bbase = (wk * 64 + fr) * 32 + sx;

  f32x4 acc[4][4] = {};
  f32x4 zacc[4] = {};
  int im0 = 1, im1 = 1, im2 = 1, im3 = 1;
  f16x8 avA[4], avB[4];

#define STAGE(bf, h_) do { \
    const size_t o0 = (size_t)(lo + (h_) / 24) * 128 * DD + (size_t)(((h_) % 24) * 32); \
    gload16(klo + o0, &Ks[bf][w * 512]); \
    gload16(khi + o0, &Ks[bf][2048 + w * 512]); \
  } while (0)

#define QLOAD(dst, dc_) do { \
    const f16* qp_ = qf + (size_t)(dc_) * 2048; \
    _Pragma("unroll") \
    for (int i = 0; i < 4; ++i) (dst)[i] = *(const f16x8*)(qp_ + i * 512); \
  } while (0)

#define MFMA_ALL(av_, bufv) do { \
    f16x8 bv[4]; \
    _Pragma("unroll") \
    for (int j = 0; j < 4; ++j) bv[j] = *(const f16x8*)&Ks[bufv][bbase + j * 512]; \
    _Pragma("unroll") \
    for (int i = 0; i < 4; ++i) \
      _Pragma("unroll") \
      for (int j = 0; j < 4; ++j) \
        acc[i][j] = __builtin_amdgcn_mfma_f32_16x16x32_f16((av_)[i], bv[j], acc[i][j], 0, 0, 0); \
  } while (0)

  // epilogue body (dc==23 for kt): per-lane exp-sum, diag capture, acc clear
#define KT_EPILOGUE(kt_) do { \
    const float mb0 = im0 ? 0.f : -1e30f; \
    const float mb1 = im1 ? 0.f : -1e30f; \
    const float mb2 = im2 ? 0.f : -1e30f; \
    const float mb3 = im3 ? 0.f : -1e30f; \
    const bool isdiag = ((kt_) == qs); \
    _Pragma("unroll") \
    for (int i = 0; i < 4; ++i) { \
      _Pragma("unroll") \
      for (int rg = 0; rg < 4; ++rg) { \
        float v0 = fmaf(acc[i][0][rg], scale, mb0); \
        float v1 = fmaf(acc[i][1][rg], scale, mb1); \
        float v2 = fmaf(acc[i][2][rg], scale, mb2); \
        float v3 = fmaf(acc[i][3][rg], scale, mb3); \
        if (isdiag) { \
          const int rl = wq * 64 + i * 16 + fq * 4 + rg; \
          const int cl = wk * 64 + fr; \
          if (cl      == rl) sdg[(size_t)bb * TT + q0 + rl] = v0; \
          if (cl + 16 == rl) sdg[(size_t)bb * TT + q0 + rl] = v1; \
          if (cl + 32 == rl) sdg[(size_t)bb * TT + q0 + rl] = v2; \
          if (cl + 48 == rl) sdg[(size_t)bb * TT + q0 + rl] = v3; \
        } \
        zacc[i][rg] += __expf(v0) + __expf(v1) + __expf(v2) + __expf(v3); \
      } \
    } \
    _Pragma("unroll") \
    for (int i = 0; i < 4; ++i) \
      _Pragma("unroll") \
      for (int j = 0; j < 4; ++j) acc[i][j] = (f32x4)(0.f); \
  } while (0)

  // prologue: stage K(h=0); prefetch avA for h=0
  STAGE(0, 0);
  QLOAD(avA, 0);
  __syncthreads();

  for (int h2 = 0; h2 < H; h2 += 2) {
    const int kt = lo + h2 / 24, dc = h2 % 24;   // dc even: 0,2,..,22
    if (dc == 0) {  // preload mask for this kt (consumed at dc==23, odd sub)
      const int kb = bb * TT + kt * 128 + wk * 64 + fr;
      im0 = mask[kb]; im1 = mask[kb + 16]; im2 = mask[kb + 32]; im3 = mask[kb + 48];
    }

    // ---- even h (buf 0): prefetch avB(dc+1) + stage K(h2+1); MFMA(avA)
    QLOAD(avB, dc + 1);
    STAGE(1, h2 + 1);
    MFMA_ALL(avA, 0);
    __syncthreads();

    // ---- odd h (buf 1): prefetch avA(next dc) + stage K(h2+2); MFMA(avB)
    if (h2 + 2 < H) {
      QLOAD(avA, (h2 + 2) % 24);
      STAGE(0, h2 + 2);
    }
    MFMA_ALL(avB, 1);

    if (dc == 22) KT_EPILOGUE(kt);   // h2+1 has dc==23

    __syncthreads();
  }
#undef STAGE
#undef QLOAD
#undef MFMA_ALL
#undef KT_EPILOGUE

  // reduce zacc across the 16 fr-lanes; write per-(kh,wk) partial Z (12 slots)
  const int slot = kh * 2 + wk;
#pragma unroll
  for (int i = 0; i < 4; ++i) {
#pragma unroll
    for (int rg = 0; rg < 4; ++rg) {
      float z = zacc[i][rg];
#pragma unroll
      for (int off = 1; off < 16; off <<= 1) z += __shfl_xor(z, off);
      if (fr == 0) {
        const int row = wq * 64 + i * 16 + fq * 4 + rg;
        pzv[(size_t)slot * MM + bb * TT + q0 + row] = z;
      }
    }
  }
}

// ---------------- merge 12 partials -> wdiag ----------------
__global__ void merge12(const float* __restrict__ pz, const float* __restrict__ sdg,
                        float* __restrict__ wdiag) {
  int i = blockIdx.x * 256 + threadIdx.x;
  if (i >= MM) return;
  float Z = 0.f;
#pragma unroll
  for (int s = 0; s < 12; ++s) Z += pz[(size_t)s * MM + i];
  wdiag[i] = __expf(sdg[i]) / Z;
}

// ---------------- output ----------------
__global__ void zero_out(float* out, int n) {
  int i = blockIdx.x * 256 + threadIdx.x;
  if (i < n) out[i] = 0.f;
}

// out[b,d] = sum_t X[b,t,d] * wdiag[b,t]
__global__ __launch_bounds__(256)
void out_gemv(const float* __restrict__ X, const float* __restrict__ wdiag,
              float* __restrict__ out) {
  __shared__ float wsm[256];
  const int b = blockIdx.z;
  const int d = blockIdx.y * 256 + threadIdx.x;
  const int tbase = blockIdx.x * 256;
  wsm[threadIdx.x] = wdiag[b * TT + tbase + threadIdx.x];
  __syncthreads();
  float acc = 0.f;
  const float* xp = X + (size_t)(b * TT + tbase) * DD + d;
#pragma unroll 4
  for (int i = 0; i < 256; ++i) acc += xp[(size_t)i * DD] * wsm[i];
  atomicAdd(&out[b * DD + d], acc);
}

extern "C" void kernel_launch(void* const* d_in, const int* in_sizes, int n_in,
                              void* d_out, int out_size, void* d_ws, size_t ws_size,
                              hipStream_t stream) {
  const float* X    = (const float*)d_in[0];
  const int*   mask = (const int*)d_in[1];
  const float* Wq_w = (const float*)d_in[2];
  const float* Wq_b = (const float*)d_in[3];
  const float* Wk_w = (const float*)d_in[4];
  const float* Wk_b = (const float*)d_in[5];
  float* out = (float*)d_out;

  // workspace layout (~103 MB):
  // [Qf 50.3MB][Kh 50.3MB][Wqh|Wkh 2.36MB -- aliased after proj by pz|sdg|wdiag
  //  (12*MM + MM + MM floats = 1.83MB <= 2.36MB)]
  f16* Qf  = (f16*)d_ws;                      // fragment-major Q
  f16* Kh  = Qf + (size_t)MM * DD;            // row-major K
  f16* Wqh = Kh + (size_t)MM * DD;            // f16 weights (dead after proj)
  f16* Wkh = Wqh + (size_t)DD * DD;
  float* pz    = (float*)Wqh;                 // alias: written by attn12 after proj reads
  float* sdg   = pz + 12 * (size_t)MM;
  float* wdiag = sdg + MM;

  cvt_f32_f16<<<288, 256, 0, stream>>>(Wq_w, Wqh, DD * DD);
  cvt_f32_f16<<<288, 256, 0, stream>>>(Wk_w, Wkh, DD * DD);

  proj_gemm<<<dim3(256, 6), 256, 0, stream>>>(X, Wqh, Wq_b, Qf, 1);
  proj_gemm<<<dim3(256, 6), 256, 0, stream>>>(X, Wkh, Wk_b, Kh, 0);

  attn12<<<1536, 256, 0, stream>>>(Qf, Kh, mask, pz, sdg);

  merge12<<<128, 256, 0, stream>>>(pz, sdg, wdiag);

  zero_out<<<24, 256, 0, stream>>>(out, BB * DD);
  out_gemv<<<dim3(16, 3, 8), 256, 0, stream>>>(X, wdiag, out);
}

// Round 15
// 418.195 us; speedup vs baseline: 5.1138x; 5.1138x over previous
//
#include <hip/hip_runtime.h>

#define BB 8
#define TT 4096
#define DD 768
#define MM (BB*TT)   // 32768

typedef _Float16 f16;
typedef _Float16 f16x8 __attribute__((ext_vector_type(8)));
typedef float f32x4 __attribute__((ext_vector_type(4)));

typedef __attribute__((address_space(1))) void void_g;
typedef __attribute__((address_space(3))) void void_l;

// async global->LDS, 16B per lane. LDS dest = wave-uniform base + lane*16 (linear).
__device__ __forceinline__ void gload16(const void* g, void* l) {
  __builtin_amdgcn_global_load_lds((void_g*)g, (void_l*)l, 16, 0, 0);
}

// ---------------- f32 -> f16 convert (for weight matrices) ----------------
__global__ void cvt_f32_f16(const float* __restrict__ in, f16* __restrict__ out, int n) {
  int i0 = (blockIdx.x * blockDim.x + threadIdx.x) * 8;
  int stride = gridDim.x * blockDim.x * 8;
  for (int i = i0; i < n; i += stride) {
    float4 a = *(const float4*)(in + i);
    float4 b = *(const float4*)(in + i + 4);
    f16x8 o;
    o[0] = (f16)a.x; o[1] = (f16)a.y; o[2] = (f16)a.z; o[3] = (f16)a.w;
    o[4] = (f16)b.x; o[5] = (f16)b.y; o[6] = (f16)b.z; o[7] = (f16)b.w;
    *(f16x8*)(out + i) = o;
  }
}

// ---------------- projection GEMM: C = A*W^T + bias -----------------------
// A: MMxDD f32 (reg-cvt staged); W: DDxDD f16 (gload16 staged, pre-swizzled
// source). frag==0: C row-major (K). frag==1: C in dc-major fragment layout:
// idx = (((row>>6)*24 + (col>>5))*4 + ((row>>4)&3))*512
//       + ((row&15) + ((col>>3)&3)*16)*8 + (col&7)
// -> wave's 4 A-fragments per dc are one contiguous 2KB run.
__global__ __launch_bounds__(256)
void proj_gemm(const float* __restrict__ Af, const f16* __restrict__ Wh,
               const float* __restrict__ bias, f16* __restrict__ C, int frag) {
  __shared__ f16 As[128 * 32];
  __shared__ f16 Ws[128 * 32];
  const int m0 = blockIdx.x * 128;
  const int n0 = blockIdx.y * 128;
  const int t = threadIdx.x;
  const int lane = t & 63;
  const int w = t >> 6;
  const int wm = (w >> 1) * 64;
  const int wn = (w & 1) * 64;
  const int fr = lane & 15, fq = lane >> 4;
  const int xst = ((t >> 3) & 3) << 3;   // A store-side swizzle (row = t>>2)
  const int xrd = ((fr >> 1) & 3) << 3;  // read-side swizzle (row = ..+fr)

  f32x4 acc[4][4] = {};

  const int e0 = t * 8;
  const int r0 = t >> 2, cA = (t & 3) * 8;
  const int e1 = 2048 + t * 8;

  // W gload16 source: linear LDS dest slot t / t+256, source col pre-swizzled
  const int c8 = ((t & 3) ^ ((t >> 3) & 3)) * 8;
  const f16* wlo = Wh + (size_t)(n0 + r0) * DD + c8;
  const f16* whi = wlo + (size_t)64 * DD;

  for (int ks = 0; ks < 24; ++ks) {
    const int k0 = ks * 32;
    // stage W (f16, async direct to LDS)
    gload16(wlo + k0, &Ws[w * 512]);
    gload16(whi + k0, &Ws[2048 + w * 512]);
    // reg-stage A with f32->f16 conversion (swizzled store)
    {
      const float* g0 = Af + (size_t)(m0 + r0) * DD + k0 + cA;
      const float* g1 = Af + (size_t)(m0 + 64 + r0) * DD + k0 + cA;
      float4 x0 = *(const float4*)g0, x1 = *(const float4*)(g0 + 4);
      float4 y0 = *(const float4*)g1, y1 = *(const float4*)(g1 + 4);
      f16x8 va, vb;
      va[0] = (f16)x0.x; va[1] = (f16)x0.y; va[2] = (f16)x0.z; va[3] = (f16)x0.w;
      va[4] = (f16)x1.x; va[5] = (f16)x1.y; va[6] = (f16)x1.z; va[7] = (f16)x1.w;
      vb[0] = (f16)y0.x; vb[1] = (f16)y0.y; vb[2] = (f16)y0.z; vb[3] = (f16)y0.w;
      vb[4] = (f16)y1.x; vb[5] = (f16)y1.y; vb[6] = (f16)y1.z; vb[7] = (f16)y1.w;
      *(f16x8*)&As[e0 ^ xst] = va;
      *(f16x8*)&As[e1 ^ xst] = vb;
    }
    __syncthreads();

    f16x8 a[4], b[4];
#pragma unroll
    for (int i = 0; i < 4; ++i)
      a[i] = *(const f16x8*)&As[(((wm + i * 16 + fr) * 32) + fq * 8) ^ xrd];
#pragma unroll
    for (int j = 0; j < 4; ++j)
      b[j] = *(const f16x8*)&Ws[(((wn + j * 16 + fr) * 32) + fq * 8) ^ xrd];
#pragma unroll
    for (int i = 0; i < 4; ++i)
#pragma unroll
      for (int j = 0; j < 4; ++j)
        acc[i][j] = __builtin_amdgcn_mfma_f32_16x16x32_f16(a[i], b[j], acc[i][j], 0, 0, 0);
    __syncthreads();
  }

#pragma unroll
  for (int j = 0; j < 4; ++j) {
    const int col = n0 + wn + j * 16 + fr;
    const float bv = bias[col];
#pragma unroll
    for (int i = 0; i < 4; ++i) {
#pragma unroll
      for (int r = 0; r < 4; ++r) {
        const int row = m0 + wm + i * 16 + fq * 4 + r;
        const f16 v = (f16)(acc[i][j][r] + bv);
        if (frag) {
          const size_t idx = (((size_t)(row >> 6) * 24 + (col >> 5)) * 4 +
                              ((row >> 4) & 3)) * 512 +
                             ((row & 15) + (((col >> 3) & 3) << 4)) * 8 + (col & 7);
          C[idx] = v;
        } else {
          C[(size_t)row * DD + col] = v;
        }
      }
    }
  }
}

// ---------------- attn13: attn11 + ring-4 K + counted vmcnt(6) ------------
// Identical math/layout to attn11 (242us best). Change: K LDS ring of 4
// half-tiles staged 2 phases ahead; per-phase barrier is vmcnt(6)+s_barrier
// (never drains the fresh stage/Q-prefetch). Invariant: at each barrier
// exactly this phase's 6 VMEM ops (4 QLOAD + 2 STAGE) are outstanding, so
// vmcnt(6) => stage needed next phase (issued 2 phases ago) has landed.
// (256,3): ~145 total regs <= 170 cap -- no spill (tripwire: WRITE_SIZE).
// Grid 768: bid = qs*24 + kh*8 + bb; kh thirds kt {11,11,10}; H = cnt*24.
__global__ __launch_bounds__(256, 3)
void attn13(const f16* __restrict__ Qf, const f16* __restrict__ K,
            const int* __restrict__ mask, float* __restrict__ pzv,
            float* __restrict__ sdg) {
  __shared__ f16 Ks[4][128 * 32];

  const int bid = blockIdx.x;
  const int qs = bid / 24;
  const int kh = (bid % 24) >> 3;
  const int bb = bid & 7;
  const int t = threadIdx.x, l = t & 63, w = t >> 6;
  const int wq = w >> 1, wk = w & 1;
  const int fr = l & 15, fq = l >> 4;
  const int q0 = qs * 128;
  const float scale = 0.036084391824351613f;  // 1/sqrt(768)
  const int lo = kh * 11;
  const int cnt = (kh < 2) ? 11 : 10;
  const int H = cnt * 24;

  const f16* Kg = K + (size_t)bb * TT * DD;

  // Qf base: 64-row group grp = bb*64 + qs*2 + wq; lane offset l*8.
  const int grp = bb * 64 + qs * 2 + wq;
  const f16* qf = Qf + (size_t)grp * 24 * 4 * 512 + (size_t)l * 8;

  // K staging: linear 16B slots t / t+256; source col-slot pre-swizzled.
  const int c8 = ((t & 3) ^ ((t >> 3) & 3)) * 8;
  const f16* klo = Kg + (size_t)(t >> 2) * DD + c8;
  const f16* khi = klo + (size_t)64 * DD;

  // K fragment read: row*32 + (fq ^ ((fr>>1)&3))*8  (conflict-free, measured)
  const int sx = (fq ^ ((fr >> 1) & 3)) * 8;
  const int bbase = (wk * 64 + fr) * 32 + sx;

  f32x4 acc[4][4] = {};
  f32x4 zacc[4] = {};
  int im0 = 1, im1 = 1, im2 = 1, im3 = 1;
  f16x8 avA[4], avB[4];

#define STAGE(h_) do { \
    if ((h_) < H) { \
      const int sl_ = (h_) & 3; \
      const size_t o0 = (size_t)(lo + (h_) / 24) * 128 * DD + (size_t)(((h_) % 24) * 32); \
      gload16(klo + o0, &Ks[sl_][w * 512]); \
      gload16(khi + o0, &Ks[sl_][2048 + w * 512]); \
    } \
  } while (0)

#define QLOAD(dst, dc_) do { \
    const f16* qp_ = qf + (size_t)(dc_) * 2048; \
    _Pragma("unroll") \
    for (int i = 0; i < 4; ++i) (dst)[i] = *(const f16x8*)(qp_ + i * 512); \
  } while (0)

#define MFMA_ALL(av_, sl_) do { \
    f16x8 bv[4]; \
    _Pragma("unroll") \
    for (int j = 0; j < 4; ++j) bv[j] = *(const f16x8*)&Ks[sl_][bbase + j * 512]; \
    _Pragma("unroll") \
    for (int i = 0; i < 4; ++i) \
      _Pragma("unroll") \
      for (int j = 0; j < 4; ++j) \
        acc[i][j] = __builtin_amdgcn_mfma_f32_16x16x32_f16((av_)[i], bv[j], acc[i][j], 0, 0, 0); \
  } while (0)

  // counted-vmcnt phase boundary (T4): never drain in-flight stage/prefetch
#define PHASE_BAR() do { \
    asm volatile("s_waitcnt vmcnt(6)" ::: "memory"); \
    __builtin_amdgcn_sched_barrier(0); \
    __builtin_amdgcn_s_barrier(); \
    __builtin_amdgcn_sched_barrier(0); \
  } while (0)

  // epilogue body (dc==23 for kt): per-lane exp-sum, diag capture, acc clear
#define KT_EPILOGUE(kt_) do { \
    const float mb0 = im0 ? 0.f : -1e30f; \
    const float mb1 = im1 ? 0.f : -1e30f; \
    const float mb2 = im2 ? 0.f : -1e30f; \
    const float mb3 = im3 ? 0.f : -1e30f; \
    const bool isdiag = ((kt_) == qs); \
    _Pragma("unroll") \
    for (int i = 0; i < 4; ++i) { \
      _Pragma("unroll") \
      for (int rg = 0; rg < 4; ++rg) { \
        float v0 = fmaf(acc[i][0][rg], scale, mb0); \
        float v1 = fmaf(acc[i][1][rg], scale, mb1); \
        float v2 = fmaf(acc[i][2][rg], scale, mb2); \
        float v3 = fmaf(acc[i][3][rg], scale, mb3); \
        if (isdiag) { \
          const int rl = wq * 64 + i * 16 + fq * 4 + rg; \
          const int cl = wk * 64 + fr; \
          if (cl      == rl) sdg[(size_t)bb * TT + q0 + rl] = v0; \
          if (cl + 16 == rl) sdg[(size_t)bb * TT + q0 + rl] = v1; \
          if (cl + 32 == rl) sdg[(size_t)bb * TT + q0 + rl] = v2; \
          if (cl + 48 == rl) sdg[(size_t)bb * TT + q0 + rl] = v3; \
        } \
        zacc[i][rg] += __expf(v0) + __expf(v1) + __expf(v2) + __expf(v3); \
      } \
    } \
    _Pragma("unroll") \
    for (int i = 0; i < 4; ++i) \
      _Pragma("unroll") \
      for (int j = 0; j < 4; ++j) acc[i][j] = (f32x4)(0.f); \
  } while (0)

  // prologue: stage slots 0,1 (phases 0,1); prefetch avA(dc=0).
  // outstanding after: STAGE0(2)+STAGE1(2)+QLOAD(4)=8; vmcnt(6) => STAGE0 done.
  STAGE(0);
  STAGE(1);
  QLOAD(avA, 0);
  PHASE_BAR();

  for (int h2 = 0; h2 < H; h2 += 2) {
    const int kt = lo + h2 / 24, dc = h2 % 24;   // dc even: 0,2,..,22
    if (dc == 0) {  // preload mask for this kt (consumed at dc==23, odd sub)
      const int kb = bb * TT + kt * 128 + wk * 64 + fr;
      im0 = mask[kb]; im1 = mask[kb + 16]; im2 = mask[kb + 32]; im3 = mask[kb + 48];
    }

    // ---- even h: QLOAD avB(dc+1) | STAGE(h2+2) | MFMA(avA, slot h2&3)
    QLOAD(avB, dc + 1);
    STAGE(h2 + 2);
    MFMA_ALL(avA, h2 & 3);
    PHASE_BAR();

    // ---- odd h: QLOAD avA(next dc) | STAGE(h2+3) | MFMA(avB, slot (h2+1)&3)
    if (h2 + 2 < H) QLOAD(avA, (h2 + 2) % 24);
    STAGE(h2 + 3);
    MFMA_ALL(avB, (h2 + 1) & 3);

    if (dc == 22) KT_EPILOGUE(kt);   // h2+1 has dc==23

    PHASE_BAR();
  }
#undef STAGE
#undef QLOAD
#undef MFMA_ALL
#undef PHASE_BAR
#undef KT_EPILOGUE

  // reduce zacc across the 16 fr-lanes; write per-(kh,wk) partial Z (6 slots)
  const int slot = kh * 2 + wk;
#pragma unroll
  for (int i = 0; i < 4; ++i) {
#pragma unroll
    for (int rg = 0; rg < 4; ++rg) {
      float z = zacc[i][rg];
#pragma unroll
      for (int off = 1; off < 16; off <<= 1) z += __shfl_xor(z, off);
      if (fr == 0) {
        const int row = wq * 64 + i * 16 + fq * 4 + rg;
        pzv[(size_t)slot * MM + bb * TT + q0 + row] = z;
      }
    }
  }
}

// ---------------- merge 6 partials -> wdiag ----------------
__global__ void merge6(const float* __restrict__ pz, const float* __restrict__ sdg,
                       float* __restrict__ wdiag) {
  int i = blockIdx.x * 256 + threadIdx.x;
  if (i >= MM) return;
  float Z = 0.f;
#pragma unroll
  for (int s = 0; s < 6; ++s) Z += pz[(size_t)s * MM + i];
  wdiag[i] = __expf(sdg[i]) / Z;
}

// ---------------- output ----------------
__global__ void zero_out(float* out, int n) {
  int i = blockIdx.x * 256 + threadIdx.x;
  if (i < n) out[i] = 0.f;
}

// out[b,d] = sum_t X[b,t,d] * wdiag[b,t]
__global__ __launch_bounds__(256)
void out_gemv(const float* __restrict__ X, const float* __restrict__ wdiag,
              float* __restrict__ out) {
  __shared__ float wsm[256];
  const int b = blockIdx.z;
  const int d = blockIdx.y * 256 + threadIdx.x;
  const int tbase = blockIdx.x * 256;
  wsm[threadIdx.x] = wdiag[b * TT + tbase + threadIdx.x];
  __syncthreads();
  float acc = 0.f;
  const float* xp = X + (size_t)(b * TT + tbase) * DD + d;
#pragma unroll 4
  for (int i = 0; i < 256; ++i) acc += xp[(size_t)i * DD] * wsm[i];
  atomicAdd(&out[b * DD + d], acc);
}

extern "C" void kernel_launch(void* const* d_in, const int* in_sizes, int n_in,
                              void* d_out, int out_size, void* d_ws, size_t ws_size,
                              hipStream_t stream) {
  const float* X    = (const float*)d_in[0];
  const int*   mask = (const int*)d_in[1];
  const float* Wq_w = (const float*)d_in[2];
  const float* Wq_b = (const float*)d_in[3];
  const float* Wk_w = (const float*)d_in[4];
  const float* Wk_b = (const float*)d_in[5];
  float* out = (float*)d_out;

  // workspace layout (~103 MB):
  // [Qf 50.3MB][Kh 50.3MB][Wqh|Wkh 2.36MB -- aliased after proj by pz|sdg|wdiag]
  f16* Qf  = (f16*)d_ws;                      // fragment-major Q
  f16* Kh  = Qf + (size_t)MM * DD;            // row-major K
  f16* Wqh = Kh + (size_t)MM * DD;            // f16 weights (dead after proj)
  f16* Wkh = Wqh + (size_t)DD * DD;
  float* pz    = (float*)Wqh;                 // alias: written by attn13 after proj reads
  float* sdg   = pz + 6 * (size_t)MM;
  float* wdiag = sdg + MM;

  cvt_f32_f16<<<288, 256, 0, stream>>>(Wq_w, Wqh, DD * DD);
  cvt_f32_f16<<<288, 256, 0, stream>>>(Wk_w, Wkh, DD * DD);

  proj_gemm<<<dim3(256, 6), 256, 0, stream>>>(X, Wqh, Wq_b, Qf, 1);
  proj_gemm<<<dim3(256, 6), 256, 0, stream>>>(X, Wkh, Wk_b, Kh, 0);

  attn13<<<768, 256, 0, stream>>>(Qf, Kh, mask, pz, sdg);

  merge6<<<128, 256, 0, stream>>>(pz, sdg, wdiag);

  zero_out<<<24, 256, 0, stream>>>(out, BB * DD);
  out_gemv<<<dim3(16, 3, 8), 256, 0, stream>>>(X, wdiag, out);
}

// Round 16
// 409.095 us; speedup vs baseline: 5.2276x; 1.0222x over previous
//
#include <hip/hip_runtime.h>

#define BB 8
#define TT 4096
#define DD 768
#define MM (BB*TT)   // 32768

typedef _Float16 f16;
typedef _Float16 f16x8 __attribute__((ext_vector_type(8)));
typedef float f32x4 __attribute__((ext_vector_type(4)));

typedef __attribute__((address_space(1))) void void_g;
typedef __attribute__((address_space(3))) void void_l;

// async global->LDS, 16B per lane. LDS dest = wave-uniform base + lane*16 (linear).
__device__ __forceinline__ void gload16(const void* g, void* l) {
  __builtin_amdgcn_global_load_lds((void_g*)g, (void_l*)l, 16, 0, 0);
}

// ---------------- f32 -> f16 convert (for weight matrices) ----------------
__global__ void cvt_f32_f16(const float* __restrict__ in, f16* __restrict__ out, int n) {
  int i0 = (blockIdx.x * blockDim.x + threadIdx.x) * 8;
  int stride = gridDim.x * blockDim.x * 8;
  for (int i = i0; i < n; i += stride) {
    float4 a = *(const float4*)(in + i);
    float4 b = *(const float4*)(in + i + 4);
    f16x8 o;
    o[0] = (f16)a.x; o[1] = (f16)a.y; o[2] = (f16)a.z; o[3] = (f16)a.w;
    o[4] = (f16)b.x; o[5] = (f16)b.y; o[6] = (f16)b.z; o[7] = (f16)b.w;
    *(f16x8*)(out + i) = o;
  }
}

// ---------------- projection GEMM v3: C = A*W^T + bias --------------------
// Tile 64m x 256n (grid 512 x 3): X re-read 3x per GEMM instead of 6x --
// halves the dominant L3 traffic. 256 thr = 4 waves (1m x 4n), per-wave
// 64x64, acc 64 AGPR; total regs ~124 <= 170 at (256,3) -- no spill.
// A: 64x32 f32 reg-cvt staged (8 f32/thread); W: 256x32 f16 via 4 gload16.
// frag==0: C row-major (K). frag==1: C in dc-major fragment layout:
// idx = (((row>>6)*24 + (col>>5))*4 + ((row>>4)&3))*512
//       + ((row&15) + ((col>>3)&3)*16)*8 + (col&7)
__global__ __launch_bounds__(256, 3)
void proj_gemm3(const float* __restrict__ Af, const f16* __restrict__ Wh,
                const float* __restrict__ bias, f16* __restrict__ C, int frag) {
  __shared__ f16 As[64 * 32];    // 4KB
  __shared__ f16 Ws[256 * 32];   // 16KB
  const int m0 = blockIdx.x * 64;
  const int n0 = blockIdx.y * 256;
  const int t = threadIdx.x;
  const int lane = t & 63;
  const int w = t >> 6;          // 0..3 -> n-cols w*64
  const int wn = w * 64;
  const int fr = lane & 15, fq = lane >> 4;
  const int xst = ((t >> 3) & 3) << 3;   // A store-side swizzle (row = t>>2)
  const int xrd = ((fr >> 1) & 3) << 3;  // read-side swizzle

  f32x4 acc[4][4] = {};

  const int r0 = t >> 2, cA = (t & 3) * 8;
  const int e0 = t * 8;          // [0, 2048)

  // W gload16 source: 4 issues cover rows r0, r0+64, r0+128, r0+192;
  // source col-slot pre-swizzled: ^((row>>1)&3) == ^((t>>3)&3).
  const int c8 = ((t & 3) ^ ((t >> 3) & 3)) * 8;
  const f16* w0 = Wh + (size_t)(n0 + r0) * DD + c8;

  for (int ks = 0; ks < 24; ++ks) {
    const int k0 = ks * 32;
    // stage W (f16, async direct to LDS): 4 x 4KB
    gload16(w0 + k0,                      &Ws[w * 512]);
    gload16(w0 + (size_t)64  * DD + k0,   &Ws[2048 + w * 512]);
    gload16(w0 + (size_t)128 * DD + k0,   &Ws[4096 + w * 512]);
    gload16(w0 + (size_t)192 * DD + k0,   &Ws[6144 + w * 512]);
    // reg-stage A with f32->f16 conversion (swizzled store): 8 f32/thread
    {
      const float* g0 = Af + (size_t)(m0 + r0) * DD + k0 + cA;
      float4 x0 = *(const float4*)g0, x1 = *(const float4*)(g0 + 4);
      f16x8 va;
      va[0] = (f16)x0.x; va[1] = (f16)x0.y; va[2] = (f16)x0.z; va[3] = (f16)x0.w;
      va[4] = (f16)x1.x; va[5] = (f16)x1.y; va[6] = (f16)x1.z; va[7] = (f16)x1.w;
      *(f16x8*)&As[e0 ^ xst] = va;
    }
    __syncthreads();

    f16x8 a[4], b[4];
#pragma unroll
    for (int i = 0; i < 4; ++i)
      a[i] = *(const f16x8*)&As[(((i * 16 + fr) * 32) + fq * 8) ^ xrd];
#pragma unroll
    for (int j = 0; j < 4; ++j)
      b[j] = *(const f16x8*)&Ws[(((wn + j * 16 + fr) * 32) + fq * 8) ^ xrd];
#pragma unroll
    for (int i = 0; i < 4; ++i)
#pragma unroll
      for (int j = 0; j < 4; ++j)
        acc[i][j] = __builtin_amdgcn_mfma_f32_16x16x32_f16(a[i], b[j], acc[i][j], 0, 0, 0);
    __syncthreads();
  }

#pragma unroll
  for (int j = 0; j < 4; ++j) {
    const int col = n0 + wn + j * 16 + fr;
    const float bv = bias[col];
#pragma unroll
    for (int i = 0; i < 4; ++i) {
#pragma unroll
      for (int r = 0; r < 4; ++r) {
        const int row = m0 + i * 16 + fq * 4 + r;
        const f16 v = (f16)(acc[i][j][r] + bv);
        if (frag) {
          const size_t idx = (((size_t)(row >> 6) * 24 + (col >> 5)) * 4 +
                              ((row >> 4) & 3)) * 512 +
                             ((row & 15) + (((col >> 3) & 3) << 4)) * 8 + (col & 7);
          C[idx] = v;
        } else {
          C[(size_t)row * DD + col] = v;
        }
      }
    }
  }
}

// ---------------- attn11: proven 242us best (reverted) --------------------
// dc-32 phases, one-phase-ahead Q prefetch, unroll-2 named ping-pong,
// K dbuf 16KB LDS, no-max Z. (256,3): 76 arch VGPR + 64 AGPR = 140 <= 170.
// Grid 768: bid = qs*24 + kh*8 + bb; kh thirds kt {11,11,10}; H = cnt*24.
__global__ __launch_bounds__(256, 3)
void attn11(const f16* __restrict__ Qf, const f16* __restrict__ K,
            const int* __restrict__ mask, float* __restrict__ pzv,
            float* __restrict__ sdg) {
  __shared__ f16 Ks[2][128 * 32];

  const int bid = blockIdx.x;
  const int qs = bid / 24;
  const int kh = (bid % 24) >> 3;
  const int bb = bid & 7;
  const int t = threadIdx.x, l = t & 63, w = t >> 6;
  const int wq = w >> 1, wk = w & 1;
  const int fr = l & 15, fq = l >> 4;
  const int q0 = qs * 128;
  const float scale = 0.036084391824351613f;  // 1/sqrt(768)
  const int lo = kh * 11;
  const int cnt = (kh < 2) ? 11 : 10;
  const int H = cnt * 24;

  const f16* Kg = K + (size_t)bb * TT * DD;

  // Qf base: 64-row group grp = bb*64 + qs*2 + wq; lane offset l*8.
  const int grp = bb * 64 + qs * 2 + wq;
  const f16* qf = Qf + (size_t)grp * 24 * 4 * 512 + (size_t)l * 8;

  // K staging: linear 16B slots t / t+256; source col-slot pre-swizzled.
  const int c8 = ((t & 3) ^ ((t >> 3) & 3)) * 8;
  const f16* klo = Kg + (size_t)(t >> 2) * DD + c8;
  const f16* khi = klo + (size_t)64 * DD;

  // K fragment read: row*32 + (fq ^ ((fr>>1)&3))*8  (conflict-free, measured)
  const int sx = (fq ^ ((fr >> 1) & 3)) * 8;
  const int bbase = (wk * 64 + fr) * 32 + sx;

  f32x4 acc[4][4] = {};
  f32x4 zacc[4] = {};
  int im0 = 1, im1 = 1, im2 = 1, im3 = 1;
  f16x8 avA[4], avB[4];

#define STAGE(bf, h_) do { \
    const size_t o0 = (size_t)(lo + (h_) / 24) * 128 * DD + (size_t)(((h_) % 24) * 32); \
    gload16(klo + o0, &Ks[bf][w * 512]); \
    gload16(khi + o0, &Ks[bf][2048 + w * 512]); \
  } while (0)

#define QLOAD(dst, dc_) do { \
    const f16* qp_ = qf + (size_t)(dc_) * 2048; \
    _Pragma("unroll") \
    for (int i = 0; i < 4; ++i) (dst)[i] = *(const f16x8*)(qp_ + i * 512); \
  } while (0)

#define MFMA_ALL(av_, bufv) do { \
    f16x8 bv[4]; \
    _Pragma("unroll") \
    for (int j = 0; j < 4; ++j) bv[j] = *(const f16x8*)&Ks[bufv][bbase + j * 512]; \
    _Pragma("unroll") \
    for (int i = 0; i < 4; ++i) \
      _Pragma("unroll") \
      for (int j = 0; j < 4; ++j) \
        acc[i][j] = __builtin_amdgcn_mfma_f32_16x16x32_f16((av_)[i], bv[j], acc[i][j], 0, 0, 0); \
  } while (0)

#define KT_EPILOGUE(kt_) do { \
    const float mb0 = im0 ? 0.f : -1e30f; \
    const float mb1 = im1 ? 0.f : -1e30f; \
    const float mb2 = im2 ? 0.f : -1e30f; \
    const float mb3 = im3 ? 0.f : -1e30f; \
    const bool isdiag = ((kt_) == qs); \
    _Pragma("unroll") \
    for (int i = 0; i < 4; ++i) { \
      _Pragma("unroll") \
      for (int rg = 0; rg < 4; ++rg) { \
        float v0 = fmaf(acc[i][0][rg], scale, mb0); \
        float v1 = fmaf(acc[i][1][rg], scale, mb1); \
        float v2 = fmaf(acc[i][2][rg], scale, mb2); \
        float v3 = fmaf(acc[i][3][rg], scale, mb3); \
        if (isdiag) { \
          const int rl = wq * 64 + i * 16 + fq * 4 + rg; \
          const int cl = wk * 64 + fr; \
          if (cl      == rl) sdg[(size_t)bb * TT + q0 + rl] = v0; \
          if (cl + 16 == rl) sdg[(size_t)bb * TT + q0 + rl] = v1; \
          if (cl + 32 == rl) sdg[(size_t)bb * TT + q0 + rl] = v2; \
          if (cl + 48 == rl) sdg[(size_t)bb * TT + q0 + rl] = v3; \
        } \
        zacc[i][rg] += __expf(v0) + __expf(v1) + __expf(v2) + __expf(v3); \
      } \
    } \
    _Pragma("unroll") \
    for (int i = 0; i < 4; ++i) \
      _Pragma("unroll") \
      for (int j = 0; j < 4; ++j) acc[i][j] = (f32x4)(0.f); \
  } while (0)

  // prologue: stage K(h=0); prefetch avA for h=0
  STAGE(0, 0);
  QLOAD(avA, 0);
  __syncthreads();

  for (int h2 = 0; h2 < H; h2 += 2) {
    const int kt = lo + h2 / 24, dc = h2 % 24;   // dc even: 0,2,..,22
    if (dc == 0) {  // preload mask for this kt (consumed at dc==23, odd sub)
      const int kb = bb * TT + kt * 128 + wk * 64 + fr;
      im0 = mask[kb]; im1 = mask[kb + 16]; im2 = mask[kb + 32]; im3 = mask[kb + 48];
    }

    // ---- even h (buf 0): prefetch avB(dc+1) + stage K(h2+1); MFMA(avA)
    QLOAD(avB, dc + 1);
    STAGE(1, h2 + 1);
    MFMA_ALL(avA, 0);
    __syncthreads();

    // ---- odd h (buf 1): prefetch avA(next dc) + stage K(h2+2); MFMA(avB)
    if (h2 + 2 < H) {
      QLOAD(avA, (h2 + 2) % 24);
      STAGE(0, h2 + 2);
    }
    MFMA_ALL(avB, 1);

    if (dc == 22) KT_EPILOGUE(kt);   // h2+1 has dc==23

    __syncthreads();
  }
#undef STAGE
#undef QLOAD
#undef MFMA_ALL
#undef KT_EPILOGUE

  // reduce zacc across the 16 fr-lanes; write per-(kh,wk) partial Z (6 slots)
  const int slot = kh * 2 + wk;
#pragma unroll
  for (int i = 0; i < 4; ++i) {
#pragma unroll
    for (int rg = 0; rg < 4; ++rg) {
      float z = zacc[i][rg];
#pragma unroll
      for (int off = 1; off < 16; off <<= 1) z += __shfl_xor(z, off);
      if (fr == 0) {
        const int row = wq * 64 + i * 16 + fq * 4 + rg;
        pzv[(size_t)slot * MM + bb * TT + q0 + row] = z;
      }
    }
  }
}

// ---------------- merge 6 partials -> wdiag ----------------
__global__ void merge6(const float* __restrict__ pz, const float* __restrict__ sdg,
                       float* __restrict__ wdiag) {
  int i = blockIdx.x * 256 + threadIdx.x;
  if (i >= MM) return;
  float Z = 0.f;
#pragma unroll
  for (int s = 0; s < 6; ++s) Z += pz[(size_t)s * MM + i];
  wdiag[i] = __expf(sdg[i]) / Z;
}

// ---------------- output ----------------
__global__ void zero_out(float* out, int n) {
  int i = blockIdx.x * 256 + threadIdx.x;
  if (i < n) out[i] = 0.f;
}

// out[b,d] = sum_t X[b,t,d] * wdiag[b,t]
__global__ __launch_bounds__(256)
void out_gemv(const float* __restrict__ X, const float* __restrict__ wdiag,
              float* __restrict__ out) {
  __shared__ float wsm[256];
  const int b = blockIdx.z;
  const int d = blockIdx.y * 256 + threadIdx.x;
  const int tbase = blockIdx.x * 256;
  wsm[threadIdx.x] = wdiag[b * TT + tbase + threadIdx.x];
  __syncthreads();
  float acc = 0.f;
  const float* xp = X + (size_t)(b * TT + tbase) * DD + d;
#pragma unroll 4
  for (int i = 0; i < 256; ++i) acc += xp[(size_t)i * DD] * wsm[i];
  atomicAdd(&out[b * DD + d], acc);
}

extern "C" void kernel_launch(void* const* d_in, const int* in_sizes, int n_in,
                              void* d_out, int out_size, void* d_ws, size_t ws_size,
                              hipStream_t stream) {
  const float* X    = (const float*)d_in[0];
  const int*   mask = (const int*)d_in[1];
  const float* Wq_w = (const float*)d_in[2];
  const float* Wq_b = (const float*)d_in[3];
  const float* Wk_w = (const float*)d_in[4];
  const float* Wk_b = (const float*)d_in[5];
  float* out = (float*)d_out;

  // workspace layout (~103 MB):
  // [Qf 50.3MB][Kh 50.3MB][Wqh|Wkh 2.36MB -- aliased after proj by pz|sdg|wdiag]
  f16* Qf  = (f16*)d_ws;                      // fragment-major Q
  f16* Kh  = Qf + (size_t)MM * DD;            // row-major K
  f16* Wqh = Kh + (size_t)MM * DD;            // f16 weights (dead after proj)
  f16* Wkh = Wqh + (size_t)DD * DD;
  float* pz    = (float*)Wqh;                 // alias: written by attn11 after proj reads
  float* sdg   = pz + 6 * (size_t)MM;
  float* wdiag = sdg + MM;

  cvt_f32_f16<<<288, 256, 0, stream>>>(Wq_w, Wqh, DD * DD);
  cvt_f32_f16<<<288, 256, 0, stream>>>(Wk_w, Wkh, DD * DD);

  proj_gemm3<<<dim3(512, 3), 256, 0, stream>>>(X, Wqh, Wq_b, Qf, 1);
  proj_gemm3<<<dim3(512, 3), 256, 0, stream>>>(X, Wkh, Wk_b, Kh, 0);

  attn11<<<768, 256, 0, stream>>>(Qf, Kh, mask, pz, sdg);

  merge6<<<128, 256, 0, stream>>>(pz, sdg, wdiag);

  zero_out<<<24, 256, 0, stream>>>(out, BB * DD);
  out_gemv<<<dim3(16, 3, 8), 256, 0, stream>>>(X, wdiag, out);
}

// Round 17
// 407.198 us; speedup vs baseline: 5.2519x; 1.0047x over previous
//
#include <hip/hip_runtime.h>

#define BB 8
#define TT 4096
#define DD 768
#define MM (BB*TT)   // 32768

typedef _Float16 f16;
typedef _Float16 f16x8 __attribute__((ext_vector_type(8)));
typedef float f32x4 __attribute__((ext_vector_type(4)));

typedef __attribute__((address_space(1))) void void_g;
typedef __attribute__((address_space(3))) void void_l;

// async global->LDS, 16B per lane. LDS dest = wave-uniform base + lane*16 (linear).
__device__ __forceinline__ void gload16(const void* g, void* l) {
  __builtin_amdgcn_global_load_lds((void_g*)g, (void_l*)l, 16, 0, 0);
}

// ---------------- f32 -> f16 convert (for weight matrices) ----------------
__global__ void cvt_f32_f16(const float* __restrict__ in, f16* __restrict__ out, int n) {
  int i0 = (blockIdx.x * blockDim.x + threadIdx.x) * 8;
  int stride = gridDim.x * blockDim.x * 8;
  for (int i = i0; i < n; i += stride) {
    float4 a = *(const float4*)(in + i);
    float4 b = *(const float4*)(in + i + 4);
    f16x8 o;
    o[0] = (f16)a.x; o[1] = (f16)a.y; o[2] = (f16)a.z; o[3] = (f16)a.w;
    o[4] = (f16)b.x; o[5] = (f16)b.y; o[6] = (f16)b.z; o[7] = (f16)b.w;
    *(f16x8*)(out + i) = o;
  }
}

// ---------------- proj Q: C = A*W^T + bias (A f32 reg-cvt; Xh write-thru) --
// Tile 64m x 256n (grid 512 x 3), 4 waves (1m x 4n). frag layout for Qf:
// idx = (((row>>6)*24 + (col>>5))*4 + ((row>>4)&3))*512
//       + ((row&15) + ((col>>3)&3)*16)*8 + (col&7)
// If Xout != nullptr, blocks with n0==0 also store the cvt'd A-tile (raw X
// in f16, row-major) -- produces Xh for the K-GEMM / gemv without a pass.
__global__ __launch_bounds__(256, 3)
void proj_gemmQ(const float* __restrict__ Af, const f16* __restrict__ Wh,
                const float* __restrict__ bias, f16* __restrict__ C,
                f16* __restrict__ Xout) {
  __shared__ f16 As[64 * 32];    // 4KB
  __shared__ f16 Ws[256 * 32];   // 16KB
  const int m0 = blockIdx.x * 64;
  const int n0 = blockIdx.y * 256;
  const int t = threadIdx.x;
  const int lane = t & 63;
  const int w = t >> 6;
  const int wn = w * 64;
  const int fr = lane & 15, fq = lane >> 4;
  const int xst = ((t >> 3) & 3) << 3;
  const int xrd = ((fr >> 1) & 3) << 3;

  f32x4 acc[4][4] = {};

  const int r0 = t >> 2, cA = (t & 3) * 8;
  const int e0 = t * 8;

  const int c8 = ((t & 3) ^ ((t >> 3) & 3)) * 8;
  const f16* w0 = Wh + (size_t)(n0 + r0) * DD + c8;
  const bool wout = (Xout != nullptr) && (n0 == 0);

  for (int ks = 0; ks < 24; ++ks) {
    const int k0 = ks * 32;
    gload16(w0 + k0,                      &Ws[w * 512]);
    gload16(w0 + (size_t)64  * DD + k0,   &Ws[2048 + w * 512]);
    gload16(w0 + (size_t)128 * DD + k0,   &Ws[4096 + w * 512]);
    gload16(w0 + (size_t)192 * DD + k0,   &Ws[6144 + w * 512]);
    {
      const float* g0 = Af + (size_t)(m0 + r0) * DD + k0 + cA;
      float4 x0 = *(const float4*)g0, x1 = *(const float4*)(g0 + 4);
      f16x8 va;
      va[0] = (f16)x0.x; va[1] = (f16)x0.y; va[2] = (f16)x0.z; va[3] = (f16)x0.w;
      va[4] = (f16)x1.x; va[5] = (f16)x1.y; va[6] = (f16)x1.z; va[7] = (f16)x1.w;
      *(f16x8*)&As[e0 ^ xst] = va;
      if (wout) *(f16x8*)&Xout[(size_t)(m0 + r0) * DD + k0 + cA] = va;
    }
    __syncthreads();

    f16x8 a[4], b[4];
#pragma unroll
    for (int i = 0; i < 4; ++i)
      a[i] = *(const f16x8*)&As[(((i * 16 + fr) * 32) + fq * 8) ^ xrd];
#pragma unroll
    for (int j = 0; j < 4; ++j)
      b[j] = *(const f16x8*)&Ws[(((wn + j * 16 + fr) * 32) + fq * 8) ^ xrd];
#pragma unroll
    for (int i = 0; i < 4; ++i)
#pragma unroll
      for (int j = 0; j < 4; ++j)
        acc[i][j] = __builtin_amdgcn_mfma_f32_16x16x32_f16(a[i], b[j], acc[i][j], 0, 0, 0);
    __syncthreads();
  }

#pragma unroll
  for (int j = 0; j < 4; ++j) {
    const int col = n0 + wn + j * 16 + fr;
    const float bv = bias[col];
#pragma unroll
    for (int i = 0; i < 4; ++i) {
#pragma unroll
      for (int r = 0; r < 4; ++r) {
        const int row = m0 + i * 16 + fq * 4 + r;
        const f16 v = (f16)(acc[i][j][r] + bv);
        const size_t idx = (((size_t)(row >> 6) * 24 + (col >> 5)) * 4 +
                            ((row >> 4) & 3)) * 512 +
                           ((row & 15) + (((col >> 3) & 3) << 4)) * 8 + (col & 7);
        C[idx] = v;
      }
    }
  }
}

// ---------------- proj K: C = A*W^T + bias, ALL-gload16 (A from Xh f16) ----
// Same geometry; zero staging VALU (A: 1 gload16, W: 4 gload16 per phase).
__global__ __launch_bounds__(256, 3)
void proj_gemmK(const f16* __restrict__ Xh, const f16* __restrict__ Wh,
                const float* __restrict__ bias, f16* __restrict__ C) {
  __shared__ f16 As[64 * 32];
  __shared__ f16 Ws[256 * 32];
  const int m0 = blockIdx.x * 64;
  const int n0 = blockIdx.y * 256;
  const int t = threadIdx.x;
  const int lane = t & 63;
  const int w = t >> 6;
  const int wn = w * 64;
  const int fr = lane & 15, fq = lane >> 4;
  const int xrd = ((fr >> 1) & 3) << 3;

  f32x4 acc[4][4] = {};

  const int r0 = t >> 2;
  const int c8 = ((t & 3) ^ ((t >> 3) & 3)) * 8;   // pre-swizzled source slot
  const f16* w0 = Wh + (size_t)(n0 + r0) * DD + c8;
  const f16* x0 = Xh + (size_t)(m0 + r0) * DD + c8;

  for (int ks = 0; ks < 24; ++ks) {
    const int k0 = ks * 32;
    gload16(x0 + k0,                      &As[w * 512]);
    gload16(w0 + k0,                      &Ws[w * 512]);
    gload16(w0 + (size_t)64  * DD + k0,   &Ws[2048 + w * 512]);
    gload16(w0 + (size_t)128 * DD + k0,   &Ws[4096 + w * 512]);
    gload16(w0 + (size_t)192 * DD + k0,   &Ws[6144 + w * 512]);
    __syncthreads();

    f16x8 a[4], b[4];
#pragma unroll
    for (int i = 0; i < 4; ++i)
      a[i] = *(const f16x8*)&As[(((i * 16 + fr) * 32) + fq * 8) ^ xrd];
#pragma unroll
    for (int j = 0; j < 4; ++j)
      b[j] = *(const f16x8*)&Ws[(((wn + j * 16 + fr) * 32) + fq * 8) ^ xrd];
#pragma unroll
    for (int i = 0; i < 4; ++i)
#pragma unroll
      for (int j = 0; j < 4; ++j)
        acc[i][j] = __builtin_amdgcn_mfma_f32_16x16x32_f16(a[i], b[j], acc[i][j], 0, 0, 0);
    __syncthreads();
  }

#pragma unroll
  for (int j = 0; j < 4; ++j) {
    const int col = n0 + wn + j * 16 + fr;
    const float bv = bias[col];
#pragma unroll
    for (int i = 0; i < 4; ++i) {
#pragma unroll
      for (int r = 0; r < 4; ++r) {
        const int row = m0 + i * 16 + fq * 4 + r;
        C[(size_t)row * DD + col] = (f16)(acc[i][j][r] + bv);
      }
    }
  }
}

// ---------------- proj fallback (K from f32 X, reg-cvt) -------------------
__global__ __launch_bounds__(256, 3)
void proj_gemm3(const float* __restrict__ Af, const f16* __restrict__ Wh,
                const float* __restrict__ bias, f16* __restrict__ C) {
  __shared__ f16 As[64 * 32];
  __shared__ f16 Ws[256 * 32];
  const int m0 = blockIdx.x * 64;
  const int n0 = blockIdx.y * 256;
  const int t = threadIdx.x;
  const int lane = t & 63;
  const int w = t >> 6;
  const int wn = w * 64;
  const int fr = lane & 15, fq = lane >> 4;
  const int xst = ((t >> 3) & 3) << 3;
  const int xrd = ((fr >> 1) & 3) << 3;
  f32x4 acc[4][4] = {};
  const int r0 = t >> 2, cA = (t & 3) * 8;
  const int e0 = t * 8;
  const int c8 = ((t & 3) ^ ((t >> 3) & 3)) * 8;
  const f16* w0 = Wh + (size_t)(n0 + r0) * DD + c8;

  for (int ks = 0; ks < 24; ++ks) {
    const int k0 = ks * 32;
    gload16(w0 + k0,                      &Ws[w * 512]);
    gload16(w0 + (size_t)64  * DD + k0,   &Ws[2048 + w * 512]);
    gload16(w0 + (size_t)128 * DD + k0,   &Ws[4096 + w * 512]);
    gload16(w0 + (size_t)192 * DD + k0,   &Ws[6144 + w * 512]);
    {
      const float* g0 = Af + (size_t)(m0 + r0) * DD + k0 + cA;
      float4 x0 = *(const float4*)g0, x1 = *(const float4*)(g0 + 4);
      f16x8 va;
      va[0] = (f16)x0.x; va[1] = (f16)x0.y; va[2] = (f16)x0.z; va[3] = (f16)x0.w;
      va[4] = (f16)x1.x; va[5] = (f16)x1.y; va[6] = (f16)x1.z; va[7] = (f16)x1.w;
      *(f16x8*)&As[e0 ^ xst] = va;
    }
    __syncthreads();
    f16x8 a[4], b[4];
#pragma unroll
    for (int i = 0; i < 4; ++i)
      a[i] = *(const f16x8*)&As[(((i * 16 + fr) * 32) + fq * 8) ^ xrd];
#pragma unroll
    for (int j = 0; j < 4; ++j)
      b[j] = *(const f16x8*)&Ws[(((wn + j * 16 + fr) * 32) + fq * 8) ^ xrd];
#pragma unroll
    for (int i = 0; i < 4; ++i)
#pragma unroll
      for (int j = 0; j < 4; ++j)
        acc[i][j] = __builtin_amdgcn_mfma_f32_16x16x32_f16(a[i], b[j], acc[i][j], 0, 0, 0);
    __syncthreads();
  }
#pragma unroll
  for (int j = 0; j < 4; ++j) {
    const int col = n0 + wn + j * 16 + fr;
    const float bv = bias[col];
#pragma unroll
    for (int i = 0; i < 4; ++i)
#pragma unroll
      for (int r = 0; r < 4; ++r) {
        const int row = m0 + i * 16 + fq * 4 + r;
        C[(size_t)row * DD + col] = (f16)(acc[i][j][r] + bv);
      }
  }
}

// ---------------- attn14: attn11 + K-step-64, barriers halved -------------
// attn11's proven prefetch discipline (one sub-step-ahead Q ping-pong) kept;
// per phase: stage 64 k-cols (4 gload16, dbuf 32KB), two sub-steps
// {QLOAD next av | 16 MFMA}, ONE barrier. 132/120 phases (vs 264 barriers).
// (256,3): ~145 total regs (incl 64 AGPR) <= 170 -- no spill (tripwire WRITE).
// Grid 768: bid = qs*24 + kh*8 + bb; kh thirds kt {11,11,10}.
__global__ __launch_bounds__(256, 3)
void attn14(const f16* __restrict__ Qf, const f16* __restrict__ K,
            const int* __restrict__ mask, float* __restrict__ pzv,
            float* __restrict__ sdg) {
  __shared__ f16 Ks[2][128 * 64];

  const int bid = blockIdx.x;
  const int qs = bid / 24;
  const int kh = (bid % 24) >> 3;
  const int bb = bid & 7;
  const int t = threadIdx.x, l = t & 63, w = t >> 6;
  const int wq = w >> 1, wk = w & 1;
  const int fr = l & 15, fq = l >> 4;
  const int q0 = qs * 128;
  const float scale = 0.036084391824351613f;  // 1/sqrt(768)
  const int lo = kh * 11;
  const int cnt = (kh < 2) ? 11 : 10;
  const int P = cnt * 12;

  const f16* Kg = K + (size_t)bb * TT * DD;

  const int grp = bb * 64 + qs * 2 + wq;
  const f16* qf = Qf + (size_t)grp * 24 * 4 * 512 + (size_t)l * 8;

  const int c8 = ((t & 3) ^ ((t >> 3) & 3)) * 8;
  const f16* klo = Kg + (size_t)(t >> 2) * DD + c8;
  const f16* khi = klo + (size_t)64 * DD;

  const int sx = (fq ^ ((fr >> 1) & 3)) * 8;
  const int bbase = (wk * 64 + fr) * 32 + sx;

  f32x4 acc[4][4] = {};
  f32x4 zacc[4] = {};
  int im0 = 1, im1 = 1, im2 = 1, im3 = 1;
  f16x8 avA[4], avB[4];

#define STAGE(bf, p_) do { \
    const size_t o0 = (size_t)(lo + (p_) / 12) * 128 * DD + (size_t)(((p_) % 12) * 64); \
    gload16(klo + o0,      &Ks[bf][w * 512]); \
    gload16(khi + o0,      &Ks[bf][2048 + w * 512]); \
    gload16(klo + o0 + 32, &Ks[bf][4096 + w * 512]); \
    gload16(khi + o0 + 32, &Ks[bf][6144 + w * 512]); \
  } while (0)

#define QLOAD(dst, dc_) do { \
    const f16* qp_ = qf + (size_t)(dc_) * 2048; \
    _Pragma("unroll") \
    for (int i = 0; i < 4; ++i) (dst)[i] = *(const f16x8*)(qp_ + i * 512); \
  } while (0)

#define MFMA_ALL(av_, bufv, off_) do { \
    f16x8 bv[4]; \
    _Pragma("unroll") \
    for (int j = 0; j < 4; ++j) bv[j] = *(const f16x8*)&Ks[bufv][(off_) + bbase + j * 512]; \
    _Pragma("unroll") \
    for (int i = 0; i < 4; ++i) \
      _Pragma("unroll") \
      for (int j = 0; j < 4; ++j) \
        acc[i][j] = __builtin_amdgcn_mfma_f32_16x16x32_f16((av_)[i], bv[j], acc[i][j], 0, 0, 0); \
  } while (0)

#define KT_EPILOGUE(kt_) do { \
    const float mb0 = im0 ? 0.f : -1e30f; \
    const float mb1 = im1 ? 0.f : -1e30f; \
    const float mb2 = im2 ? 0.f : -1e30f; \
    const float mb3 = im3 ? 0.f : -1e30f; \
    const bool isdiag = ((kt_) == qs); \
    _Pragma("unroll") \
    for (int i = 0; i < 4; ++i) { \
      _Pragma("unroll") \
      for (int rg = 0; rg < 4; ++rg) { \
        float v0 = fmaf(acc[i][0][rg], scale, mb0); \
        float v1 = fmaf(acc[i][1][rg], scale, mb1); \
        float v2 = fmaf(acc[i][2][rg], scale, mb2); \
        float v3 = fmaf(acc[i][3][rg], scale, mb3); \
        if (isdiag) { \
          const int rl = wq * 64 + i * 16 + fq * 4 + rg; \
          const int cl = wk * 64 + fr; \
          if (cl      == rl) sdg[(size_t)bb * TT + q0 + rl] = v0; \
          if (cl + 16 == rl) sdg[(size_t)bb * TT + q0 + rl] = v1; \
          if (cl + 32 == rl) sdg[(size_t)bb * TT + q0 + rl] = v2; \
          if (cl + 48 == rl) sdg[(size_t)bb * TT + q0 + rl] = v3; \
        } \
        zacc[i][rg] += __expf(v0) + __expf(v1) + __expf(v2) + __expf(v3); \
      } \
    } \
    _Pragma("unroll") \
    for (int i = 0; i < 4; ++i) \
      _Pragma("unroll") \
      for (int j = 0; j < 4; ++j) acc[i][j] = (f32x4)(0.f); \
  } while (0)

  // prologue: stage phase 0; prefetch avA (dc=0)
  STAGE(0, 0);
  QLOAD(avA, 0);
  __syncthreads();

  for (int p = 0; p < P; ++p) {
    const int buf = p & 1;
    const int kt = lo + p / 12, c = p % 12;   // phase covers dcs 2c, 2c+1
    if (c == 0) {  // preload mask for this kt (consumed at c==11)
      const int kb = bb * TT + kt * 128 + wk * 64 + fr;
      im0 = mask[kb]; im1 = mask[kb + 16]; im2 = mask[kb + 32]; im3 = mask[kb + 48];
    }

    // ---- sub A: prefetch avB(dc 2c+1), stage next phase; MFMA(avA, cols 0-31)
    QLOAD(avB, 2 * c + 1);
    if (p + 1 < P) STAGE(buf ^ 1, p + 1);
    MFMA_ALL(avA, buf, 0);

    // ---- sub B: prefetch avA(next phase dc), MFMA(avB, cols 32-63)
    if (p + 1 < P) QLOAD(avA, 2 * (((p + 1) % 12)));
    MFMA_ALL(avB, buf, 4096);

    if (c == 11) KT_EPILOGUE(kt);

    __syncthreads();
  }
#undef STAGE
#undef QLOAD
#undef MFMA_ALL
#undef KT_EPILOGUE

  // reduce zacc across the 16 fr-lanes; write per-(kh,wk) partial Z (6 slots)
  const int slot = kh * 2 + wk;
#pragma unroll
  for (int i = 0; i < 4; ++i) {
#pragma unroll
    for (int rg = 0; rg < 4; ++rg) {
      float z = zacc[i][rg];
#pragma unroll
      for (int off = 1; off < 16; off <<= 1) z += __shfl_xor(z, off);
      if (fr == 0) {
        const int row = wq * 64 + i * 16 + fq * 4 + rg;
        pzv[(size_t)slot * MM + bb * TT + q0 + row] = z;
      }
    }
  }
}

// ---------------- merge 6 partials -> wdiag ----------------
__global__ void merge6(const float* __restrict__ pz, const float* __restrict__ sdg,
                       float* __restrict__ wdiag) {
  int i = blockIdx.x * 256 + threadIdx.x;
  if (i >= MM) return;
  float Z = 0.f;
#pragma unroll
  for (int s = 0; s < 6; ++s) Z += pz[(size_t)s * MM + i];
  wdiag[i] = __expf(sdg[i]) / Z;
}

// ---------------- output ----------------
__global__ void zero_out(float* out, int n) {
  int i = blockIdx.x * 256 + threadIdx.x;
  if (i < n) out[i] = 0.f;
}

// out[b,d] = sum_t X[b,t,d] * wdiag[b,t]  (f32 X fallback)
__global__ __launch_bounds__(256)
void out_gemv(const float* __restrict__ X, const float* __restrict__ wdiag,
              float* __restrict__ out) {
  __shared__ float wsm[256];
  const int b = blockIdx.z;
  const int d = blockIdx.y * 256 + threadIdx.x;
  const int tbase = blockIdx.x * 256;
  wsm[threadIdx.x] = wdiag[b * TT + tbase + threadIdx.x];
  __syncthreads();
  float acc = 0.f;
  const float* xp = X + (size_t)(b * TT + tbase) * DD + d;
#pragma unroll 4
  for (int i = 0; i < 256; ++i) acc += xp[(size_t)i * DD] * wsm[i];
  atomicAdd(&out[b * DD + d], acc);
}

// out[b,d] = sum_t Xh[b,t,d] * wdiag[b,t]  (f16 X, half the traffic)
__global__ __launch_bounds__(256)
void out_gemv_h(const f16* __restrict__ Xh, const float* __restrict__ wdiag,
                float* __restrict__ out) {
  __shared__ float wsm[256];
  const int b = blockIdx.z;
  const int d = blockIdx.y * 256 + threadIdx.x;
  const int tbase = blockIdx.x * 256;
  wsm[threadIdx.x] = wdiag[b * TT + tbase + threadIdx.x];
  __syncthreads();
  float acc = 0.f;
  const f16* xp = Xh + (size_t)(b * TT + tbase) * DD + d;
#pragma unroll 4
  for (int i = 0; i < 256; ++i) acc += (float)xp[(size_t)i * DD] * wsm[i];
  atomicAdd(&out[b * DD + d], acc);
}

extern "C" void kernel_launch(void* const* d_in, const int* in_sizes, int n_in,
                              void* d_out, int out_size, void* d_ws, size_t ws_size,
                              hipStream_t stream) {
  const float* X    = (const float*)d_in[0];
  const int*   mask = (const int*)d_in[1];
  const float* Wq_w = (const float*)d_in[2];
  const float* Wq_b = (const float*)d_in[3];
  const float* Wk_w = (const float*)d_in[4];
  const float* Wk_b = (const float*)d_in[5];
  float* out = (float*)d_out;

  const size_t n2 = (size_t)MM * DD;              // 25.17M f16 elems
  const size_t wreg = 2 * (size_t)DD * DD;        // 2 weight mats (f16 elems)
  const size_t need_full = (3 * n2 + wreg) * sizeof(f16);  // ~153.4 MB
  const bool useXh = ws_size >= need_full;

  f16* Qf  = (f16*)d_ws;                          // fragment-major Q
  f16* Kh  = Qf + n2;                             // row-major K
  f16* Xh  = useXh ? (Kh + n2) : nullptr;         // f16 copy of X
  f16* Wqh = useXh ? (Xh + n2) : (Kh + n2);       // f16 weights (dead after proj)
  f16* Wkh = Wqh + (size_t)DD * DD;
  float* pz    = (float*)Wqh;                     // alias after proj reads
  float* sdg   = pz + 6 * (size_t)MM;
  float* wdiag = sdg + MM;

  cvt_f32_f16<<<288, 256, 0, stream>>>(Wq_w, Wqh, DD * DD);
  cvt_f32_f16<<<288, 256, 0, stream>>>(Wk_w, Wkh, DD * DD);

  proj_gemmQ<<<dim3(512, 3), 256, 0, stream>>>(X, Wqh, Wq_b, Qf, Xh);
  if (useXh)
    proj_gemmK<<<dim3(512, 3), 256, 0, stream>>>(Xh, Wkh, Wk_b, Kh);
  else
    proj_gemm3<<<dim3(512, 3), 256, 0, stream>>>(X, Wkh, Wk_b, Kh);

  attn14<<<768, 256, 0, stream>>>(Qf, Kh, mask, pz, sdg);

  merge6<<<128, 256, 0, stream>>>(pz, sdg, wdiag);

  zero_out<<<24, 256, 0, stream>>>(out, BB * DD);
  if (useXh)
    out_gemv_h<<<dim3(16, 3, 8), 256, 0, stream>>>(Xh, wdiag, out);
  else
    out_gemv<<<dim3(16, 3, 8), 256, 0, stream>>>(X, wdiag, out);
}